// Round 5
// baseline (301.105 us; speedup 1.0000x reference)
//
#include <hip/hip_runtime.h>
#include <float.h>

#define B_SZ   64
#define T_FR   20
#define K_SEL  5
#define C_CH   3
#define D_SKIM 245760
#define HW224  50176
#define F4_IMG 12544        // HW224/4
#define K1_BLOCKS 768
#define K1_TILES  10        // 768 blocks * 10 tiles * BK32 == 245760
#define BK        32
#define GP_PARTS  4
#define F4_PART   3136      // F4_IMG/4

// compile-time float4 component pick (dp is an unrolled literal)
#define AC(v, dp) ((dp) == 0 ? (v).x : (dp) == 1 ? (v).y : (dp) == 2 ? (v).z : (v).w)

// ---------------------------------------------------------------------------
// Kernel 1: fea partials + fused policy/top-k.
// GEMM: 768 blocks (3/CU, exactly co-resident) x 10 tiles of BK=32.
// Ring-3 LDS buffers + counted vmcnt(4) (prefetch stays in flight across the
// barrier -- T3/T4 pattern) + ONE raw s_barrier per tile:
//   [wait vmcnt(4); s_barrier; STAGE(t+2); compute(t)]
// WAR safety: STAGE(t+2) overwrites buf[(t-1)%3], whose readers (compute t-1)
// all passed this iteration's barrier. Data safety: each wave waits its own
// vmcnt before the barrier, so buf[t%3] is fully landed for everyone.
// A staged via pre-swizzled global source (slot ^= row>>3) -> conflict-free
// 8-row-strided b128 reads; W linear [32][64] (2-way alias = free).
// Fused policy: arrival counter; the last 64 arrivals each spin until all 768
// slabs are released, then reduce one batch row (fixed order -> deterministic),
// compute logits, stable top-5 (strict >, ties -> lowest idx = jax.lax.top_k).
// ---------------------------------------------------------------------------
__global__ __launch_bounds__(256) void skim_policy(
    const float* __restrict__ A, const float* __restrict__ W,
    float* __restrict__ partial, const float* __restrict__ b_skim,
    const float* __restrict__ W_pol, const float* __restrict__ b_pol,
    int* __restrict__ idx_out, int* __restrict__ cnt) {
  __shared__ float lds[12288];         // 3 bufs x (A 2048 dw | W 2048 dw)
  __shared__ int s_arr;
  const int t    = threadIdx.x;
  const int lane = t & 63;
  const int wav  = t >> 6;             // 0..3
  const int kb   = lane >> 3;          // 0..7 (b-group)
  const int b0   = kb << 3;
  const int j0   = (lane & 7) << 3;

  // staging geometry (per wave: 2 A-DMA + 2 W-DMA, 1KB each)
  const int ga0    = 2 * wav;
  const int arow0  = 8 * ga0 + (lane >> 3);
  const int aslot0 = (lane & 7) ^ (ga0 & 7);
  const int arow1  = 8 * (ga0 + 1) + (lane >> 3);
  const int aslot1 = (lane & 7) ^ ((ga0 + 1) & 7);
  const int wrow0  = 4 * ga0 + (lane >> 4);
  const int wcol0  = (lane & 15) << 2;
  const int wrow1  = 4 * (ga0 + 1) + (lane >> 4);

  float acc[8][8];
#pragma unroll
  for (int i = 0; i < 8; ++i)
#pragma unroll
    for (int j = 0; j < 8; ++j) acc[i][j] = 0.f;

  const long dbase = (long)blockIdx.x * (K1_TILES * BK);

#define STAGE(bufsel, tile_)                                                   \
  {                                                                            \
    const long d0_ = dbase + (long)(tile_) * BK;                               \
    float* Ab = lds + (bufsel) * 4096;                                         \
    float* Wb = Ab + 2048;                                                     \
    __builtin_amdgcn_global_load_lds(                                          \
        (const __attribute__((address_space(1))) void*)(A + (long)arow0 * D_SKIM + d0_ + aslot0 * 4), \
        (__attribute__((address_space(3))) void*)(Ab + ga0 * 256), 16, 0, 0);  \
    __builtin_amdgcn_global_load_lds(                                          \
        (const __attribute__((address_space(1))) void*)(A + (long)arow1 * D_SKIM + d0_ + aslot1 * 4), \
        (__attribute__((address_space(3))) void*)(Ab + (ga0 + 1) * 256), 16, 0, 0); \
    __builtin_amdgcn_global_load_lds(                                          \
        (const __attribute__((address_space(1))) void*)(W + (d0_ + wrow0) * 64 + wcol0), \
        (__attribute__((address_space(3))) void*)(Wb + ga0 * 256), 16, 0, 0);  \
    __builtin_amdgcn_global_load_lds(                                          \
        (const __attribute__((address_space(1))) void*)(W + (d0_ + wrow1) * 64 + wcol0), \
        (__attribute__((address_space(3))) void*)(Wb + (ga0 + 1) * 256), 16, 0, 0); \
  }

  STAGE(0, 0)
  STAGE(1, 1)

  for (int tile = 0; tile < K1_TILES; ++tile) {
    if (tile < K1_TILES - 1) {
      asm volatile("s_waitcnt vmcnt(4)" ::: "memory");   // tile t landed; t+1 in flight
    } else {
      asm volatile("s_waitcnt vmcnt(0)" ::: "memory");
    }
    __builtin_amdgcn_sched_barrier(0);
    __builtin_amdgcn_s_barrier();
    if (tile + 2 < K1_TILES) STAGE((tile + 2) % 3, tile + 2)
    const float* Ab = lds + (tile % 3) * 4096;
    const float* Wb = Ab + 2048;
#pragma unroll
    for (int chunk = 0; chunk < 2; ++chunk) {
      const int dc = (wav << 3) + (chunk << 2);
      const int sw = dc ^ (kb << 2);
      const float4 a0 = *reinterpret_cast<const float4*>(&Ab[(b0 + 0) * 32 + sw]);
      const float4 a1 = *reinterpret_cast<const float4*>(&Ab[(b0 + 1) * 32 + sw]);
      const float4 a2 = *reinterpret_cast<const float4*>(&Ab[(b0 + 2) * 32 + sw]);
      const float4 a3 = *reinterpret_cast<const float4*>(&Ab[(b0 + 3) * 32 + sw]);
      const float4 a4 = *reinterpret_cast<const float4*>(&Ab[(b0 + 4) * 32 + sw]);
      const float4 a5 = *reinterpret_cast<const float4*>(&Ab[(b0 + 5) * 32 + sw]);
      const float4 a6 = *reinterpret_cast<const float4*>(&Ab[(b0 + 6) * 32 + sw]);
      const float4 a7 = *reinterpret_cast<const float4*>(&Ab[(b0 + 7) * 32 + sw]);
#pragma unroll
      for (int dp = 0; dp < 4; ++dp) {
        const float4 wlo = *reinterpret_cast<const float4*>(&Wb[(dc + dp) * 64 + j0]);
        const float4 whi = *reinterpret_cast<const float4*>(&Wb[(dc + dp) * 64 + j0 + 4]);
#define FMA_ROW(i, av)                             \
        acc[i][0] = fmaf(av, wlo.x, acc[i][0]);    \
        acc[i][1] = fmaf(av, wlo.y, acc[i][1]);    \
        acc[i][2] = fmaf(av, wlo.z, acc[i][2]);    \
        acc[i][3] = fmaf(av, wlo.w, acc[i][3]);    \
        acc[i][4] = fmaf(av, whi.x, acc[i][4]);    \
        acc[i][5] = fmaf(av, whi.y, acc[i][5]);    \
        acc[i][6] = fmaf(av, whi.z, acc[i][6]);    \
        acc[i][7] = fmaf(av, whi.w, acc[i][7]);
        FMA_ROW(0, AC(a0, dp)) FMA_ROW(1, AC(a1, dp))
        FMA_ROW(2, AC(a2, dp)) FMA_ROW(3, AC(a3, dp))
        FMA_ROW(4, AC(a4, dp)) FMA_ROW(5, AC(a5, dp))
        FMA_ROW(6, AC(a6, dp)) FMA_ROW(7, AC(a7, dp))
#undef FMA_ROW
      }
    }
  }
#undef STAGE

  // ---- cross-wave reduce reusing LDS buffers 0 and 1 ----
  __syncthreads();
  float* reg = lds + ((wav & 1) ? 4096 : 0);
  if (wav < 2) {
#pragma unroll
    for (int i = 0; i < 8; ++i) {
      *reinterpret_cast<float4*>(&reg[(b0 + i) * 64 + j0])     =
          make_float4(acc[i][0], acc[i][1], acc[i][2], acc[i][3]);
      *reinterpret_cast<float4*>(&reg[(b0 + i) * 64 + j0 + 4]) =
          make_float4(acc[i][4], acc[i][5], acc[i][6], acc[i][7]);
    }
  }
  __syncthreads();
  if (wav >= 2) {
#pragma unroll
    for (int i = 0; i < 8; ++i) {
      float4 lo = *reinterpret_cast<const float4*>(&reg[(b0 + i) * 64 + j0]);
      float4 hi = *reinterpret_cast<const float4*>(&reg[(b0 + i) * 64 + j0 + 4]);
      lo.x += acc[i][0]; lo.y += acc[i][1]; lo.z += acc[i][2]; lo.w += acc[i][3];
      hi.x += acc[i][4]; hi.y += acc[i][5]; hi.z += acc[i][6]; hi.w += acc[i][7];
      *reinterpret_cast<float4*>(&reg[(b0 + i) * 64 + j0])     = lo;
      *reinterpret_cast<float4*>(&reg[(b0 + i) * 64 + j0 + 4]) = hi;
    }
  }
  __syncthreads();
  {
    const float4* r0 = reinterpret_cast<const float4*>(lds);
    const float4* r1 = reinterpret_cast<const float4*>(lds + 4096);
    float4* outp = reinterpret_cast<float4*>(partial + (long)blockIdx.x * 4096);
#pragma unroll
    for (int k = 0; k < 4; ++k) {
      const int e = t + k * 256;
      float4 v0 = r0[e], v1 = r1[e];
      outp[e] = make_float4(v0.x + v1.x, v0.y + v1.y, v0.z + v1.z, v0.w + v1.w);
    }
  }

  // ---- fused policy: arrival counter, last 64 blocks each do one row ----
  __syncthreads();                     // all slab stores issued block-wide
  if (t == 0)
    s_arr = __hip_atomic_fetch_add(cnt, 1, __ATOMIC_ACQ_REL, __HIP_MEMORY_SCOPE_AGENT);
  __syncthreads();
  const int arr = s_arr;
  if (arr < K1_BLOCKS - B_SZ) return;
  const int b = arr - (K1_BLOCKS - B_SZ);

  if (t == 0) {
    while (__hip_atomic_load(cnt, __ATOMIC_ACQUIRE, __HIP_MEMORY_SCOPE_AGENT) < K1_BLOCKS) {}
  }
  __syncthreads();

  float* red  = lds;                   // [4][64]
  float* vsh  = lds + 256;             // [64]
  float* lgsh = lds + 320;             // [20]
  const int P4 = K1_BLOCKS / 4;
  const float* base = partial + (long)(wav * P4) * 4096 + b * 64 + lane;
  float ssum = 0.f;
#pragma unroll 16
  for (int p = 0; p < P4; ++p) ssum += base[(long)p * 4096];
  red[wav * 64 + lane] = ssum;
  __syncthreads();

  if (wav == 0) {
    float fea = ((red[lane] + red[64 + lane]) + (red[128 + lane] + red[192 + lane]))
                + b_skim[lane];
    vsh[lane] = fmaxf(fea, 0.f);
  }
  __syncthreads();

  if (t < 20) {
    float lg = b_pol[t];
#pragma unroll 8
    for (int k = 0; k < 64; ++k) lg = fmaf(vsh[k], W_pol[k * 20 + t], lg);
    lgsh[t] = lg;
  }
  __syncthreads();

  if (t == 0) {
    float lg[20];
#pragma unroll
    for (int i = 0; i < 20; ++i) lg[i] = lgsh[i];
    int sel[K_SEL];
#pragma unroll
    for (int s5 = 0; s5 < K_SEL; ++s5) {
      int bi = 0; float bv = lg[0];
      for (int i = 1; i < 20; ++i)
        if (lg[i] > bv) { bv = lg[i]; bi = i; }
      sel[s5] = bi; lg[bi] = -FLT_MAX;
    }
#pragma unroll
    for (int a = 1; a < K_SEL; ++a) {
      int v = sel[a], c = a;
      while (c > 0 && sel[c - 1] > v) { sel[c] = sel[c - 1]; --c; }
      sel[c] = v;
    }
#pragma unroll
    for (int s5 = 0; s5 < K_SEL; ++s5) idx_out[b * K_SEL + s5] = sel[s5];
  }
}

// ---------------------------------------------------------------------------
// Kernel 2: gather+pool partials, fused eval. 3840 blocks (15/CU).
// Per (b,s,c,part) block: partial spatial sum -> pooled_part[blk]; per-b
// arrival counter; the 60th arrival (acquire) computes output row b.
// ---------------------------------------------------------------------------
__global__ __launch_bounds__(256) void gather_eval(
    const float* __restrict__ F224, const int* __restrict__ idx,
    float* __restrict__ pooled_part, const float* __restrict__ W_eval,
    const float* __restrict__ b_eval, float* __restrict__ out,
    int* __restrict__ cnt2) {
  const int blk  = blockIdx.x;
  const int part = blk & 3;
  const int img  = blk >> 2;           // b*15 + s*3 + c
  const int b = img / 15;
  const int r = img % 15;
  const int s = r / 3;
  const int c = r % 3;
  const int fr = idx[b * K_SEL + s];
  const float4* p4 = reinterpret_cast<const float4*>(F224) +
      ((long)(b * T_FR + fr) * C_CH + c) * F4_IMG + part * F4_PART;
  float sum = 0.f;
#pragma unroll 4
  for (int i = threadIdx.x; i < F4_PART; i += 256) {
    float4 v = p4[i];
    sum += (v.x + v.y) + (v.z + v.w);
  }
#pragma unroll
  for (int off = 32; off; off >>= 1) sum += __shfl_down(sum, off);
  __shared__ float red[4];
  __shared__ int s_arr;
  if ((threadIdx.x & 63) == 0) red[threadIdx.x >> 6] = sum;
  __syncthreads();
  if (threadIdx.x == 0) {
    pooled_part[blk] = (red[0] + red[1]) + (red[2] + red[3]);
    s_arr = __hip_atomic_fetch_add(&cnt2[b], 1, __ATOMIC_ACQ_REL, __HIP_MEMORY_SCOPE_AGENT);
  }
  __syncthreads();
  if (s_arr != GP_PARTS * K_SEL * C_CH - 1) return;   // only the 60th arrival

  // ---- fused eval for row b ----
  const int t = threadIdx.x;
  __shared__ float sh[60];
  __shared__ float pk[15];
  if (t < 60) sh[t] = pooled_part[b * 60 + t];
  __syncthreads();
  if (t < 15)
    pk[t] = ((sh[t * 4] + sh[t * 4 + 1]) + (sh[t * 4 + 2] + sh[t * 4 + 3]))
            * (1.0f / HW224);
  __syncthreads();
  for (int n = t; n < 400; n += 256) {
    float o = b_eval[n];
#pragma unroll
    for (int k = 0; k < 15; ++k) o = fmaf(pk[k], W_eval[k * 400 + n], o);
    out[b * 400 + n] = o;
  }
}

// ---------------------------------------------------------------------------
extern "C" void kernel_launch(void* const* d_in, const int* in_sizes, int n_in,
                              void* d_out, int out_size, void* d_ws, size_t ws_size,
                              hipStream_t stream) {
  const float* F64    = (const float*)d_in[0];
  const float* F224   = (const float*)d_in[1];
  const float* W_skim = (const float*)d_in[2];
  const float* b_skim = (const float*)d_in[3];
  const float* W_pol  = (const float*)d_in[4];
  const float* b_pol  = (const float*)d_in[5];
  const float* W_eval = (const float*)d_in[6];
  const float* b_eval = (const float*)d_in[7];
  float* out = (float*)d_out;

  char* ws = (char*)d_ws;
  int*   cnt1        = (int*)ws;                 // 1 int
  int*   cnt2        = (int*)(ws + 64);          // 64 ints
  int*   idx         = (int*)(ws + 512);         // 320 ints
  float* pooled_part = (float*)(ws + 2048);      // 960 floats
  float* partial     = (float*)(ws + 65536);     // 768*4096 floats

  hipMemsetAsync(ws, 0, 512, stream);            // zero counters every call
  skim_policy<<<K1_BLOCKS, 256, 0, stream>>>(F64, W_skim, partial, b_skim,
                                             W_pol, b_pol, idx, cnt1);
  gather_eval<<<B_SZ * K_SEL * C_CH * GP_PARTS, 256, 0, stream>>>(
      F224, idx, pooled_part, W_eval, b_eval, out, cnt2);
}

// Round 6
// 88.476 us; speedup vs baseline: 3.4032x; 3.4032x over previous
//
#include <hip/hip_runtime.h>
#include <float.h>

#define B_SZ   64
#define T_FR   20
#define K_SEL  5
#define C_CH   3
#define D_SKIM 245760
#define HW224  50176
#define F4_IMG 12544        // HW224/4
#define K1_BLOCKS 768
#define K1_TILES  10        // 768 blocks * 10 tiles * BK32 == 245760
#define BK        32
#define GP_PARTS  4
#define F4_PART   3136      // F4_IMG/4

// compile-time float4 component pick (dp is an unrolled literal)
#define AC(v, dp) ((dp) == 0 ? (v).x : (dp) == 1 ? (v).y : (dp) == 2 ? (v).z : (v).w)

// ---------------------------------------------------------------------------
// Kernel 1: per-block partial of fea = A[64,245760] @ W[245760,64].
// 768 blocks (3/CU) x 10 tiles of BK=32. Ring-3 LDS buffers, counted
// vmcnt(4) (prefetch stays in flight across the barrier - T3/T4 pattern),
// ONE raw s_barrier per tile:  [wait vmcnt(4); s_barrier; STAGE(t+2);
// compute(t)].  WAR safety: STAGE(t+2) overwrites buf[(t-1)%3] whose readers
// all passed this barrier. Data safety: each wave waits for its own 4 DMAs of
// tile t before the barrier, so after the barrier buf[t%3] is fully landed.
// A staged via pre-swizzled global source (slot ^= instr-id) -> conflict-free
// 8-row-strided b128 reads; W linear [32][64] (2-way alias = free).
// This round: PURE BISECT of R5 - identical main loop, NO fusion/spin tail.
// ---------------------------------------------------------------------------
__global__ __launch_bounds__(256) void skim_gemm(
    const float* __restrict__ A, const float* __restrict__ W,
    float* __restrict__ partial) {
  __shared__ float lds[12288];         // 3 bufs x (A 2048 dw | W 2048 dw)
  const int t    = threadIdx.x;
  const int lane = t & 63;
  const int wav  = t >> 6;             // 0..3
  const int kb   = lane >> 3;          // 0..7 (b-group)
  const int b0   = kb << 3;
  const int j0   = (lane & 7) << 3;

  // staging geometry (per wave: 2 A-DMA + 2 W-DMA, 1KB each)
  const int ga0    = 2 * wav;
  const int arow0  = 8 * ga0 + (lane >> 3);
  const int aslot0 = (lane & 7) ^ (ga0 & 7);
  const int arow1  = 8 * (ga0 + 1) + (lane >> 3);
  const int aslot1 = (lane & 7) ^ ((ga0 + 1) & 7);
  const int wrow0  = 4 * ga0 + (lane >> 4);
  const int wcol0  = (lane & 15) << 2;
  const int wrow1  = 4 * (ga0 + 1) + (lane >> 4);

  float acc[8][8];
#pragma unroll
  for (int i = 0; i < 8; ++i)
#pragma unroll
    for (int j = 0; j < 8; ++j) acc[i][j] = 0.f;

  const long dbase = (long)blockIdx.x * (K1_TILES * BK);

#define STAGE(bufsel, tile_)                                                   \
  {                                                                            \
    const long d0_ = dbase + (long)(tile_) * BK;                               \
    float* Ab = lds + (bufsel) * 4096;                                         \
    float* Wb = Ab + 2048;                                                     \
    __builtin_amdgcn_global_load_lds(                                          \
        (const __attribute__((address_space(1))) void*)(A + (long)arow0 * D_SKIM + d0_ + aslot0 * 4), \
        (__attribute__((address_space(3))) void*)(Ab + ga0 * 256), 16, 0, 0);  \
    __builtin_amdgcn_global_load_lds(                                          \
        (const __attribute__((address_space(1))) void*)(A + (long)arow1 * D_SKIM + d0_ + aslot1 * 4), \
        (__attribute__((address_space(3))) void*)(Ab + (ga0 + 1) * 256), 16, 0, 0); \
    __builtin_amdgcn_global_load_lds(                                          \
        (const __attribute__((address_space(1))) void*)(W + (d0_ + wrow0) * 64 + wcol0), \
        (__attribute__((address_space(3))) void*)(Wb + ga0 * 256), 16, 0, 0);  \
    __builtin_amdgcn_global_load_lds(                                          \
        (const __attribute__((address_space(1))) void*)(W + (d0_ + wrow1) * 64 + wcol0), \
        (__attribute__((address_space(3))) void*)(Wb + (ga0 + 1) * 256), 16, 0, 0); \
  }

  STAGE(0, 0)
  STAGE(1, 1)

  for (int tile = 0; tile < K1_TILES; ++tile) {
    if (tile < K1_TILES - 1) {
      asm volatile("s_waitcnt vmcnt(4)" ::: "memory");   // tile t landed; t+1 in flight
    } else {
      asm volatile("s_waitcnt vmcnt(0)" ::: "memory");
    }
    __builtin_amdgcn_sched_barrier(0);
    __builtin_amdgcn_s_barrier();
    __builtin_amdgcn_sched_barrier(0);               // keep ds_reads below barrier
    if (tile + 2 < K1_TILES) STAGE((tile + 2) % 3, tile + 2)
    const float* Ab = lds + (tile % 3) * 4096;
    const float* Wb = Ab + 2048;
#pragma unroll
    for (int chunk = 0; chunk < 2; ++chunk) {
      const int dc = (wav << 3) + (chunk << 2);
      const int sw = dc ^ (kb << 2);
      const float4 a0 = *reinterpret_cast<const float4*>(&Ab[(b0 + 0) * 32 + sw]);
      const float4 a1 = *reinterpret_cast<const float4*>(&Ab[(b0 + 1) * 32 + sw]);
      const float4 a2 = *reinterpret_cast<const float4*>(&Ab[(b0 + 2) * 32 + sw]);
      const float4 a3 = *reinterpret_cast<const float4*>(&Ab[(b0 + 3) * 32 + sw]);
      const float4 a4 = *reinterpret_cast<const float4*>(&Ab[(b0 + 4) * 32 + sw]);
      const float4 a5 = *reinterpret_cast<const float4*>(&Ab[(b0 + 5) * 32 + sw]);
      const float4 a6 = *reinterpret_cast<const float4*>(&Ab[(b0 + 6) * 32 + sw]);
      const float4 a7 = *reinterpret_cast<const float4*>(&Ab[(b0 + 7) * 32 + sw]);
#pragma unroll
      for (int dp = 0; dp < 4; ++dp) {
        const float4 wlo = *reinterpret_cast<const float4*>(&Wb[(dc + dp) * 64 + j0]);
        const float4 whi = *reinterpret_cast<const float4*>(&Wb[(dc + dp) * 64 + j0 + 4]);
#define FMA_ROW(i, av)                             \
        acc[i][0] = fmaf(av, wlo.x, acc[i][0]);    \
        acc[i][1] = fmaf(av, wlo.y, acc[i][1]);    \
        acc[i][2] = fmaf(av, wlo.z, acc[i][2]);    \
        acc[i][3] = fmaf(av, wlo.w, acc[i][3]);    \
        acc[i][4] = fmaf(av, whi.x, acc[i][4]);    \
        acc[i][5] = fmaf(av, whi.y, acc[i][5]);    \
        acc[i][6] = fmaf(av, whi.z, acc[i][6]);    \
        acc[i][7] = fmaf(av, whi.w, acc[i][7]);
        FMA_ROW(0, AC(a0, dp)) FMA_ROW(1, AC(a1, dp))
        FMA_ROW(2, AC(a2, dp)) FMA_ROW(3, AC(a3, dp))
        FMA_ROW(4, AC(a4, dp)) FMA_ROW(5, AC(a5, dp))
        FMA_ROW(6, AC(a6, dp)) FMA_ROW(7, AC(a7, dp))
#undef FMA_ROW
      }
    }
  }
#undef STAGE

  // ---- 2-round cross-wave reduce reusing LDS buffers 0 and 1 ----
  __syncthreads();
  float* reg = lds + ((wav & 1) ? 4096 : 0);
  if (wav < 2) {
#pragma unroll
    for (int i = 0; i < 8; ++i) {
      *reinterpret_cast<float4*>(&reg[(b0 + i) * 64 + j0])     =
          make_float4(acc[i][0], acc[i][1], acc[i][2], acc[i][3]);
      *reinterpret_cast<float4*>(&reg[(b0 + i) * 64 + j0 + 4]) =
          make_float4(acc[i][4], acc[i][5], acc[i][6], acc[i][7]);
    }
  }
  __syncthreads();
  if (wav >= 2) {
#pragma unroll
    for (int i = 0; i < 8; ++i) {
      float4 lo = *reinterpret_cast<const float4*>(&reg[(b0 + i) * 64 + j0]);
      float4 hi = *reinterpret_cast<const float4*>(&reg[(b0 + i) * 64 + j0 + 4]);
      lo.x += acc[i][0]; lo.y += acc[i][1]; lo.z += acc[i][2]; lo.w += acc[i][3];
      hi.x += acc[i][4]; hi.y += acc[i][5]; hi.z += acc[i][6]; hi.w += acc[i][7];
      *reinterpret_cast<float4*>(&reg[(b0 + i) * 64 + j0])     = lo;
      *reinterpret_cast<float4*>(&reg[(b0 + i) * 64 + j0 + 4]) = hi;
    }
  }
  __syncthreads();
  const float4* r0 = reinterpret_cast<const float4*>(lds);
  const float4* r1 = reinterpret_cast<const float4*>(lds + 4096);
  float4* outp = reinterpret_cast<float4*>(partial + (long)blockIdx.x * 4096);
#pragma unroll
  for (int k = 0; k < 4; ++k) {
    const int e = t + k * 256;
    float4 v0 = r0[e], v1 = r1[e];
    outp[e] = make_float4(v0.x + v1.x, v0.y + v1.y, v0.z + v1.z, v0.w + v1.w);
  }
}

// ---------------------------------------------------------------------------
// Kernel 2: reduce 768 partial slabs -> fea; relu(+b_skim); logits via W_pol;
// stable top-5 (strict >, lowest index on ties = jax.lax.top_k), sorted asc.
// ---------------------------------------------------------------------------
__global__ __launch_bounds__(256) void policy_topk(
    const float* __restrict__ partial, const float* __restrict__ b_skim,
    const float* __restrict__ W_pol, const float* __restrict__ b_pol,
    int* __restrict__ idx_out) {
  const int b    = blockIdx.x;
  const int t    = threadIdx.x;
  const int lane = t & 63;
  const int wav  = t >> 6;
  __shared__ float red[4][64];
  __shared__ float vsh[64];
  __shared__ float lgsh[20];

  const int P4 = K1_BLOCKS / 4;        // 192 slabs per wave
  const float* base = partial + (long)(wav * P4) * 4096 + b * 64 + lane;
  float s = 0.f;
#pragma unroll 16
  for (int p = 0; p < P4; ++p) s += base[(long)p * 4096];
  red[wav][lane] = s;
  __syncthreads();

  if (wav == 0) {
    float fea = ((red[0][lane] + red[1][lane]) + (red[2][lane] + red[3][lane]))
                + b_skim[lane];
    vsh[lane] = fmaxf(fea, 0.f);
  }
  __syncthreads();

  if (t < 20) {
    float lg = b_pol[t];
#pragma unroll 8
    for (int k = 0; k < 64; ++k) lg = fmaf(vsh[k], W_pol[k * 20 + t], lg);
    lgsh[t] = lg;
  }
  __syncthreads();

  if (t == 0) {
    float lg[20];
#pragma unroll
    for (int i = 0; i < 20; ++i) lg[i] = lgsh[i];
    int sel[K_SEL];
#pragma unroll
    for (int s5 = 0; s5 < K_SEL; ++s5) {
      int bi = 0; float bv = lg[0];
      for (int i = 1; i < 20; ++i)
        if (lg[i] > bv) { bv = lg[i]; bi = i; }
      sel[s5] = bi; lg[bi] = -FLT_MAX;
    }
#pragma unroll
    for (int a = 1; a < K_SEL; ++a) {
      int v = sel[a], c = a;
      while (c > 0 && sel[c - 1] > v) { sel[c] = sel[c - 1]; --c; }
      sel[c] = v;
    }
#pragma unroll
    for (int s5 = 0; s5 < K_SEL; ++s5) idx_out[b * K_SEL + s5] = sel[s5];
  }
}

// ---------------------------------------------------------------------------
// Kernel 3: partial spatial sums of the 5 selected frames.
// 4 parts per (b,s,c) image -> 3840 blocks == 15 blocks/CU (no tail).
// ---------------------------------------------------------------------------
__global__ __launch_bounds__(256) void gather_pool(
    const float* __restrict__ F224, const int* __restrict__ idx,
    float* __restrict__ pooled_part) {
  const int blk  = blockIdx.x;
  const int part = blk & 3;
  const int img  = blk >> 2;           // b*15 + s*3 + c
  const int b = img / 15;
  const int r = img % 15;
  const int s = r / 3;
  const int c = r % 3;
  const int fr = idx[b * K_SEL + s];
  const float4* p4 = reinterpret_cast<const float4*>(F224) +
      ((long)(b * T_FR + fr) * C_CH + c) * F4_IMG + part * F4_PART;
  float sum = 0.f;
#pragma unroll 4
  for (int i = threadIdx.x; i < F4_PART; i += 256) {
    float4 v = p4[i];
    sum += (v.x + v.y) + (v.z + v.w);
  }
#pragma unroll
  for (int off = 32; off; off >>= 1) sum += __shfl_down(sum, off);
  __shared__ float red[4];
  if ((threadIdx.x & 63) == 0) red[threadIdx.x >> 6] = sum;
  __syncthreads();
  if (threadIdx.x == 0) pooled_part[blk] = (red[0] + red[1]) + (red[2] + red[3]);
}

// ---------------------------------------------------------------------------
// Kernel 4: out[b][n] = b_eval[n] + sum_k pooled[b][k] * W_eval[k][n]
// ---------------------------------------------------------------------------
__global__ __launch_bounds__(512) void eval_gemm(
    const float* __restrict__ pooled_part, const float* __restrict__ W_eval,
    const float* __restrict__ b_eval, float* __restrict__ out) {
  const int b = blockIdx.x;
  const int t = threadIdx.x;
  __shared__ float sh[60];
  __shared__ float pk[15];
  if (t < 60) sh[t] = pooled_part[b * 60 + t];
  __syncthreads();
  if (t < 15)
    pk[t] = ((sh[t * 4] + sh[t * 4 + 1]) + (sh[t * 4 + 2] + sh[t * 4 + 3]))
            * (1.0f / HW224);
  __syncthreads();
  if (t < 400) {
    float o = b_eval[t];
#pragma unroll
    for (int k = 0; k < 15; ++k) o = fmaf(pk[k], W_eval[k * 400 + t], o);
    out[b * 400 + t] = o;
  }
}

// ---------------------------------------------------------------------------
extern "C" void kernel_launch(void* const* d_in, const int* in_sizes, int n_in,
                              void* d_out, int out_size, void* d_ws, size_t ws_size,
                              hipStream_t stream) {
  const float* F64    = (const float*)d_in[0];
  const float* F224   = (const float*)d_in[1];
  const float* W_skim = (const float*)d_in[2];
  const float* b_skim = (const float*)d_in[3];
  const float* W_pol  = (const float*)d_in[4];
  const float* b_pol  = (const float*)d_in[5];
  const float* W_eval = (const float*)d_in[6];
  const float* b_eval = (const float*)d_in[7];
  float* out = (float*)d_out;

  char* ws = (char*)d_ws;
  float* partial     = (float*)ws;                         // 768*4096 floats
  int*   idx         = (int*)(ws + (size_t)K1_BLOCKS * 4096 * 4);
  float* pooled_part = (float*)(ws + (size_t)K1_BLOCKS * 4096 * 4 + 1280);

  skim_gemm  <<<K1_BLOCKS, 256, 0, stream>>>(F64, W_skim, partial);
  policy_topk<<<B_SZ, 256, 0, stream>>>(partial, b_skim, W_pol, b_pol, idx);
  gather_pool<<<B_SZ * K_SEL * C_CH * GP_PARTS, 256, 0, stream>>>(F224, idx, pooled_part);
  eval_gemm  <<<B_SZ, 512, 0, stream>>>(pooled_part, W_eval, b_eval, out);
}